// Round 4
// baseline (126.077 us; speedup 1.0000x reference)
//
#include <hip/hip_runtime.h>
#include <math.h>

#define B_DIM 8
#define T_DIM 1024
#define D_DIM 512
#define BT (B_DIM * T_DIM)   // 8192
#define NBLK 512             // band blocks: 8 batches x 64 tiles
#define LROW 520             // LDS row stride in ushorts (1040 B -> bank stride 4)

typedef __bf16 bf16x8 __attribute__((ext_vector_type(8)));
typedef float floatx4 __attribute__((ext_vector_type(4)));

__device__ __forceinline__ float wave_reduce_sum(float v) {
#pragma unroll
    for (int off = 32; off > 0; off >>= 1) v += __shfl_xor(v, off, 64);
    return v;
}

// fp32 -> bf16 round-to-nearest-even (validated rounds 1-3)
__device__ __forceinline__ ushort f2bf(float x) {
    unsigned u = __float_as_uint(x);
    return (ushort)((u + 0x7fffu + ((u >> 16) & 1u)) >> 16);
}

__device__ __forceinline__ float softplus(float y) {
    return fmaxf(y, 0.0f) + log1pf(expf(-fabsf(y)));
}

// monotonic float -> uint key (order-preserving incl. negatives)
__device__ __forceinline__ unsigned fkey(float f) {
    unsigned u = __float_as_uint(f);
    return (u & 0x80000000u) ? ~u : (u | 0x80000000u);
}

// One kernel: stage+normalize 64 rows to LDS, MFMA 16x48 band tile,
// fused two-direction loss + argmax, cross-block combine via device atomics;
// last-finishing block reduces the column keys and writes out[0..1].
__global__ __launch_bounds__(256) void fused_kernel(
    const float* __restrict__ m, const float* __restrict__ a,
    const float* __restrict__ pscale, const float* __restrict__ pbias,
    unsigned* __restrict__ colkey, float* __restrict__ gloss,
    float* __restrict__ gcorr, unsigned* __restrict__ done,
    float* __restrict__ out)
{
    __shared__ char smraw[64 * LROW * 2];            // 66560 B
    ushort* stage  = (ushort*)smraw;                 // [64][LROW] bf16 rows
    float*  red    = (float*)smraw;                  // [4][3][256] (aliases stage)
    float*  Sbuf   = (float*)(smraw + 12288);        // [16][48]
    float*  rowpos = (float*)(smraw + 15360);        // [16]
    float*  shl    = (float*)(smraw + 15424);        // [4]
    int*    lflag  = (int*)(smraw + 15440);

    int blk = blockIdx.x;
    int b   = blk >> 6;
    int t0  = (blk & 63) << 4;
    int tid  = threadIdx.x;
    int w    = tid >> 6;
    int lane = tid & 63;

    const float* mbase = m + ((size_t)b * T_DIM) * D_DIM;
    const float* abase = a + ((size_t)b * T_DIM) * D_DIM;

    // ---- stage 1: load fp32, normalize, bf16 -> LDS ----
    // wave 0: m rows t0..t0+15 (u 0..15); waves 1-3: a rows t0-16..t0+31 (u 16..63)
#pragma unroll
    for (int i0 = 0; i0 < 16; i0 += 4) {
        float4 da[4], db[4];
        float ss[4];
#pragma unroll
        for (int r = 0; r < 4; ++r) {
            int u = w * 16 + i0 + r;
            const float4* p;
            if (u < 16) {
                p = (const float4*)(mbase + (size_t)(t0 + u) * D_DIM);
            } else {
                int gr = t0 - 16 + (u - 16);
                gr = min(max(gr, 0), T_DIM - 1);   // clamp; outputs masked later
                p = (const float4*)(abase + (size_t)gr * D_DIM);
            }
            da[r] = p[lane]; db[r] = p[lane + 64];
            ss[r] = da[r].x*da[r].x + da[r].y*da[r].y + da[r].z*da[r].z + da[r].w*da[r].w
                  + db[r].x*db[r].x + db[r].y*db[r].y + db[r].z*db[r].z + db[r].w*db[r].w;
        }
#pragma unroll
        for (int off = 32; off > 0; off >>= 1) {
#pragma unroll
            for (int r = 0; r < 4; ++r) ss[r] += __shfl_xor(ss[r], off, 64);
        }
#pragma unroll
        for (int r = 0; r < 4; ++r) {
            int u = w * 16 + i0 + r;
            float inv = 1.0f / fmaxf(sqrtf(ss[r]), 1e-12f);
            ushort4 o0 = { f2bf(da[r].x*inv), f2bf(da[r].y*inv),
                           f2bf(da[r].z*inv), f2bf(da[r].w*inv) };
            ushort4 o1 = { f2bf(db[r].x*inv), f2bf(db[r].y*inv),
                           f2bf(db[r].z*inv), f2bf(db[r].w*inv) };
            *(ushort4*)&stage[u * LROW + lane * 4]       = o0;  // elems 4*lane
            *(ushort4*)&stage[u * LROW + 256 + lane * 4] = o1;  // elems 256+4*lane
        }
    }
    __syncthreads();

    // ---- stage 2: MFMA band, k-split across 4 waves ----
    int mrow = lane & 15, kgrp = lane >> 4;
    int koff = w * 128 + kgrp * 8;
    const ushort* Am = &stage[mrow * LROW + koff];          // m row t0+mrow
    const ushort* B0 = &stage[(16 + mrow) * LROW + koff];   // a row t0-16+mrow
    const ushort* B1 = &stage[(32 + mrow) * LROW + koff];   // a row t0+mrow
    const ushort* B2 = &stage[(48 + mrow) * LROW + koff];   // a row t0+16+mrow
    floatx4 acc0 = {0,0,0,0}, acc1 = {0,0,0,0}, acc2 = {0,0,0,0};
#pragma unroll
    for (int ks = 0; ks < 4; ++ks) {
        bf16x8 af = *(const bf16x8*)(Am + ks * 32);
        bf16x8 f0 = *(const bf16x8*)(B0 + ks * 32);
        bf16x8 f1 = *(const bf16x8*)(B1 + ks * 32);
        bf16x8 f2 = *(const bf16x8*)(B2 + ks * 32);
        acc0 = __builtin_amdgcn_mfma_f32_16x16x32_bf16(af, f0, acc0, 0, 0, 0);
        acc1 = __builtin_amdgcn_mfma_f32_16x16x32_bf16(af, f1, acc1, 0, 0, 0);
        acc2 = __builtin_amdgcn_mfma_f32_16x16x32_bf16(af, f2, acc2, 0, 0, 0);
    }
    __syncthreads();   // stage region dead; red region live from here

    // k-split reduce through LDS. C layout: col=lane&15, row=(lane>>4)*4+reg
#pragma unroll
    for (int r = 0; r < 4; ++r) {
        int rr = (kgrp * 4 + r) * 16 + mrow;
        red[(w * 3 + 0) * 256 + rr] = acc0[r];
        red[(w * 3 + 1) * 256 + rr] = acc1[r];
        red[(w * 3 + 2) * 256 + rr] = acc2[r];
    }
    __syncthreads();

    int i  = tid >> 4;   // local row t-t0
    int cc = tid & 15;   // col within j-tile
    float s[3];
#pragma unroll
    for (int jt = 0; jt < 3; ++jt)
        s[jt] = red[(0*3+jt)*256 + tid] + red[(1*3+jt)*256 + tid]
              + red[(2*3+jt)*256 + tid] + red[(3*3+jt)*256 + tid];
#pragma unroll
    for (int jt = 0; jt < 3; ++jt)
        Sbuf[i * 48 + jt * 16 + cc] = s[jt];

    // ---- fused loss epilogue (identical masks to validated round 3) ----
    float scale = expf(pscale[0]), bias = pbias[0];
    float loss = 0.0f;
    float mmax = -1e30f, mpos = 0.0f;
#pragma unroll
    for (int jt = 0; jt < 3; ++jt) {
        int k  = jt * 16 + cc;
        int dd = k - i;                 // diag + 16
        int c  = t0 - 16 + k;
        bool cv = (c >= 0) && (c < T_DIM);
        if (cv && dd >= 0 && dd <= 32) {
            float logit = s[jt] * scale + bias;
            if (dd < 32) {              // m2a entry
                bool pos = (dd >= 12) && (dd <= 19);
                loss += softplus(pos ? -logit : logit);
                if (s[jt] > mmax) { mmax = s[jt]; mpos = pos ? 1.0f : 0.0f; }
            }
            if (dd > 0) {               // a2m entry
                bool pos = (dd >= 13) && (dd <= 20);
                loss += softplus(pos ? -logit : logit);
            }
        }
    }

    // m2a per-row argmax across 16 cc-lanes
#pragma unroll
    for (int off = 1; off < 16; off <<= 1) {
        float ov = __shfl_xor(mmax, off, 64);
        float op = __shfl_xor(mpos, off, 64);
        if (ov > mmax) { mmax = ov; mpos = op; }
    }
    if (cc == 0) rowpos[i] = mpos;

    loss = wave_reduce_sum(loss);
    if (lane == 0) shl[w] = loss;
    __syncthreads();

    // a2m per-column partial max over this block's 16 rows -> atomicMax
    if (tid < 48) {
        int k = tid;
        int c = t0 - 16 + k;
        if (c >= 0 && c < T_DIM) {
            float bv = -1e30f; float bp = 0.0f;
            int ilo = max(0, k - 32), ihi = min(16, k);
            for (int ii = ilo; ii < ihi; ++ii) {       // ascending r: first-wins
                float v = Sbuf[ii * 48 + k];
                if (v > bv) {
                    bv = v;
                    int dd = k - ii;
                    bp = (dd >= 13 && dd <= 20) ? 1.0f : 0.0f;
                }
            }
            unsigned key = (fkey(bv) & ~1u) | (bp > 0.5f ? 1u : 0u);
            atomicMax(&colkey[(b << 10) + c], key);
        }
    }
    if (tid == 0) {
        float Lb = shl[0] + shl[1] + shl[2] + shl[3];
        float Cb = 0.0f;
        for (int r = 0; r < 16; ++r) Cb += rowpos[r];
        atomicAdd(gloss, Lb);
        atomicAdd(gcorr, Cb);
    }

    // ---- last-block combine ----
    __threadfence();
    __syncthreads();
    if (tid == 0) lflag[0] = (atomicAdd(done, 1u) == (unsigned)(NBLK - 1)) ? 1 : 0;
    __syncthreads();
    if (lflag[0]) {
        __threadfence();
        float c2 = 0.0f;
        for (int x = tid; x < BT; x += 256) {
            unsigned k = __hip_atomic_load(&colkey[x], __ATOMIC_RELAXED,
                                           __HIP_MEMORY_SCOPE_AGENT);
            c2 += (float)(k & 1u);
        }
        c2 = wave_reduce_sum(c2);
        if (lane == 0) shl[w] = c2;
        __syncthreads();
        if (tid == 0) {
            float C2 = shl[0] + shl[1] + shl[2] + shl[3];
            float L  = __hip_atomic_load(gloss, __ATOMIC_RELAXED,
                                         __HIP_MEMORY_SCOPE_AGENT);
            float C1 = __hip_atomic_load(gcorr, __ATOMIC_RELAXED,
                                         __HIP_MEMORY_SCOPE_AGENT);
            out[0] = L / 16384.0f;          // (m2a+a2m)/(2T), mean over B folded
            out[1] = (C1 + C2) / 16384.0f;  // (m2a+a2m)/(2*T*B)
        }
    }
}

extern "C" void kernel_launch(void* const* d_in, const int* in_sizes, int n_in,
                              void* d_out, int out_size, void* d_ws, size_t ws_size,
                              hipStream_t stream)
{
    const float* m  = (const float*)d_in[0];
    const float* a  = (const float*)d_in[1];
    const float* ps = (const float*)d_in[2];
    const float* pb = (const float*)d_in[3];
    float* out = (float*)d_out;

    unsigned* colkey = (unsigned*)d_ws;          // BT keys
    float*    gloss  = (float*)(colkey + BT);
    float*    gcorr  = gloss + 1;
    unsigned* done   = (unsigned*)(gcorr + 1);

    // zero accumulators + keys (0 == key of most-negative float) + done counter
    hipMemsetAsync(d_ws, 0, (size_t)(BT + 3) * sizeof(unsigned), stream);
    fused_kernel<<<NBLK, 256, 0, stream>>>(m, a, ps, pb,
                                           colkey, gloss, gcorr, done, out);
}